// Round 1
// baseline (41.939 us; speedup 1.0000x reference)
//
#include <hip/hip_runtime.h>
#include <hip/hip_bf16.h>
#include <math.h>

#define B_IMG 16
#define H_DIM 640
#define W_DIM 640
#define NROWS (B_IMG * H_DIM)
#define NPIX  ((float)B_IMG * H_DIM * W_DIM)
#define LOSS_WEIGHT 0.1f
#define LN2F 0.69314718055994530942f
#define MAXACT 256

// ---------------------------------------------------------------------------
// Kernel A: box rasterization + per-image bucketing + eff flags. One block.
// ---------------------------------------------------------------------------
__global__ void setup_boxes(const float* __restrict__ bboxes,
                            const int* __restrict__ batch_idx,
                            const unsigned char* __restrict__ is_seg,
                            int M,
                            int* __restrict__ cnt,       // [B]
                            int4* __restrict__ boxlist,  // [B*M], stride M
                            int* __restrict__ eff,       // [B]
                            int* __restrict__ meta)      // [2]: n_eff, any_eff
{
    __shared__ int scnt[B_IMG];
    __shared__ int seff[B_IMG];
    const int tid = threadIdx.x;
    if (tid < B_IMG) scnt[tid] = 0;
    __syncthreads();

    for (int m = tid; m < M; m += blockDim.x) {
        // Match reference exactly: f32 math, clip to [0, dim-1], trunc cast.
        float cx = bboxes[4*m+0] * (float)W_DIM;
        float cy = bboxes[4*m+1] * (float)H_DIM;
        float bw = bboxes[4*m+2] * (float)W_DIM;
        float bh = bboxes[4*m+3] * (float)H_DIM;
        int x1 = (int)fminf(fmaxf(cx - bw*0.5f, 0.0f), (float)(W_DIM-1));
        int y1 = (int)fminf(fmaxf(cy - bh*0.5f, 0.0f), (float)(H_DIM-1));
        int x2 = (int)fminf(fmaxf(cx + bw*0.5f, 0.0f), (float)(W_DIM-1));
        int y2 = (int)fminf(fmaxf(cy + bh*0.5f, 0.0f), (float)(H_DIM-1));
        int b  = batch_idx[m];
        b = min(max(b, 0), B_IMG-1);
        int p = atomicAdd(&scnt[b], 1);          // LDS atomic, order irrelevant (union)
        boxlist[b*M + p] = make_int4(x1, y1, x2, y2);
    }
    __syncthreads();

    if (tid < B_IMG) {
        int c = scnt[tid];
        cnt[tid] = c;
        // is_seg is all-false in this dataset; reading as bytes is correct for
        // either 1-byte-bool or little-endian-int32-zero storage.
        int e = (is_seg[tid] == 0 && c > 0) ? 1 : 0;
        seff[tid] = e;
        eff[tid]  = e;
    }
    __syncthreads();
    if (tid == 0) {
        int ne = 0;
        for (int b = 0; b < B_IMG; ++b) ne += seff[b];
        meta[0] = ne;
        meta[1] = (ne > 0) ? 1 : 0;
    }
}

// ---------------------------------------------------------------------------
// Kernel B: one block per (image, row). Accumulate softplus(v) and masked v.
// ---------------------------------------------------------------------------
__global__ void __launch_bounds__(256)
row_reduce(const float* __restrict__ seg,
           const int* __restrict__ cnt,
           const int4* __restrict__ boxlist,
           const int* __restrict__ eff,
           int M,
           float2* __restrict__ partial)   // [NROWS]
{
    const int r   = blockIdx.x;            // r = b*H + y
    const int b   = r / H_DIM;
    const int y   = r - b * H_DIM;
    const int tid = threadIdx.x;

    if (eff[b] == 0) {
        // Non-effective image: contribution is ln2/pixel, added analytically
        // in the final kernel. Just zero the partial slot.
        if (tid == 0) partial[r] = make_float2(0.0f, 0.0f);
        return;
    }

    __shared__ int  s_nact;
    __shared__ int2 s_int[MAXACT];         // active x-intervals for this row
    __shared__ float red1[256];
    __shared__ float red2[256];

    if (tid == 0) s_nact = 0;
    __syncthreads();

    const int nb = cnt[b];
    for (int i = tid; i < nb; i += 256) {
        int4 bx = boxlist[b*M + i];        // (x1,y1,x2,y2)
        if (y >= bx.y && y <= bx.w) {
            int p = atomicAdd(&s_nact, 1);
            if (p < MAXACT) s_int[p] = make_int2(bx.x, bx.z);
        }
    }
    __syncthreads();
    const int na = min(s_nact, MAXACT);

    float sp_sum = 0.0f;   // sum softplus(v)
    float mx_sum = 0.0f;   // sum v over union-of-boxes pixels
    const float* rowp = seg + (size_t)r * W_DIM;

    for (int x = tid; x < W_DIM; x += 256) {
        float v  = rowp[x];
        float sp = fmaxf(v, 0.0f) + log1pf(expf(-fabsf(v)));
        sp_sum += sp;
        bool t = false;
        for (int i = 0; i < na; ++i) {
            int2 iv = s_int[i];
            t |= (x >= iv.x && x <= iv.y);
        }
        if (t) mx_sum += v;
    }

    red1[tid] = sp_sum;
    red2[tid] = mx_sum;
    __syncthreads();
    for (int s = 128; s > 0; s >>= 1) {    // fixed-order tree: deterministic
        if (tid < s) { red1[tid] += red1[tid + s]; red2[tid] += red2[tid + s]; }
        __syncthreads();
    }
    if (tid == 0) partial[r] = make_float2(red1[0], red2[0]);
}

// ---------------------------------------------------------------------------
// Kernel C: deterministic final reduction + loss assembly. One block.
// ---------------------------------------------------------------------------
__global__ void __launch_bounds__(1024)
final_reduce(const float2* __restrict__ partial,
             const int* __restrict__ meta,
             float* __restrict__ out)
{
    __shared__ float s1[1024];
    __shared__ float s2[1024];
    const int tid = threadIdx.x;
    float a1 = 0.0f, a2 = 0.0f;
    for (int i = tid; i < NROWS; i += 1024) {   // fixed per-thread order
        float2 p = partial[i];
        a1 += p.x; a2 += p.y;
    }
    s1[tid] = a1; s2[tid] = a2;
    __syncthreads();
    for (int s = 512; s > 0; s >>= 1) {
        if (tid < s) { s1[tid] += s1[tid + s]; s2[tid] += s2[tid + s]; }
        __syncthreads();
    }
    if (tid == 0) {
        int n_eff   = meta[0];
        int any_eff = meta[1];
        float noneff_px = (float)(B_IMG - n_eff) * (float)H_DIM * (float)W_DIM;
        float total = s1[0] - s2[0] + LN2F * noneff_px;
        float loss  = LOSS_WEIGHT * (total / NPIX);
        out[0] = any_eff ? loss : 0.0f;
    }
}

// ---------------------------------------------------------------------------
extern "C" void kernel_launch(void* const* d_in, const int* in_sizes, int n_in,
                              void* d_out, int out_size, void* d_ws, size_t ws_size,
                              hipStream_t stream) {
    const float*         seg       = (const float*)d_in[0];
    const float*         bboxes    = (const float*)d_in[1];
    const int*           batch_idx = (const int*)d_in[2];
    const unsigned char* is_seg    = (const unsigned char*)d_in[3];
    float*               out       = (float*)d_out;
    const int M = in_sizes[1] / 4;

    char* ws = (char*)d_ws;
    size_t off = 0;
    int* cnt = (int*)(ws + off);                 off += B_IMG * sizeof(int);
    off = (off + 15) & ~(size_t)15;
    int4* boxlist = (int4*)(ws + off);           off += (size_t)B_IMG * M * sizeof(int4);
    int* eff = (int*)(ws + off);                 off += B_IMG * sizeof(int);
    int* meta = (int*)(ws + off);                off += 2 * sizeof(int);
    off = (off + 15) & ~(size_t)15;
    float2* partial = (float2*)(ws + off);       off += (size_t)NROWS * sizeof(float2);

    setup_boxes<<<1, 256, 0, stream>>>(bboxes, batch_idx, is_seg, M,
                                       cnt, boxlist, eff, meta);
    row_reduce<<<NROWS, 256, 0, stream>>>(seg, cnt, boxlist, eff, M, partial);
    final_reduce<<<1, 1024, 0, stream>>>(partial, meta, out);
}

// Round 2
// 26.143 us; speedup vs baseline: 1.6042x; 1.6042x over previous
//
#include <hip/hip_runtime.h>
#include <hip/hip_bf16.h>
#include <math.h>

#define B_IMG 16
#define H_DIM 640
#define W_DIM 640
#define W4    (W_DIM / 4)          // 160 float4 per row
#define IMG4  (H_DIM * W4)         // 102400 float4 per image
#define T4    (B_IMG * IMG4)       // 1638400 float4 total
#define NPIX  ((float)B_IMG * H_DIM * W_DIM)
#define LOSS_WEIGHT 0.1f
#define LN2F 0.69314718055994530942f
#define GRID 2048
#define NT   256
#define MAXBOX 1024                // >= M (dataset M = 256)

__device__ __forceinline__ float softplus_fast(float v) {
    // matches max(v,0) + log1p(exp(-|v|)) to ~1e-7 abs; budget is 1.6e-3 on a scalar
    return fmaxf(v, 0.0f) + __logf(1.0f + __expf(-fabsf(v)));
}

// ---------------------------------------------------------------------------
// Kernel 1: fused rasterize + streaming reduce. GRID blocks x NT threads.
// Each block independently rasterizes the M boxes into LDS (counting-sorted
// per image) and grid-strides the pixels as float4.
// ---------------------------------------------------------------------------
__global__ void __launch_bounds__(NT)
fused_reduce(const float4* __restrict__ seg4,
             const float*  __restrict__ bboxes,
             const int*    __restrict__ batch_idx,
             const unsigned char* __restrict__ is_seg,
             int M,
             float2* __restrict__ partial)     // [GRID]
{
    __shared__ int  s_cnt[B_IMG];
    __shared__ int  s_start[B_IMG];
    __shared__ int  s_eff[B_IMG];
    __shared__ int2 s_yiv[MAXBOX];             // (y1,y2) per box, image-sorted
    __shared__ int2 s_xiv[MAXBOX];             // (x1,x2)
    __shared__ float red1[NT / 64];
    __shared__ float red2[NT / 64];

    const int tid = threadIdx.x;
    if (tid < B_IMG) s_cnt[tid] = 0;
    __syncthreads();

    // --- rasterize boxes (f32 math, clip [0,dim-1], trunc — matches ref) ---
    // M <= 4*NT supported with statically-unrolled per-thread slots.
    int  my_b[4], my_p[4];
    int2 my_y[4], my_x[4];
#pragma unroll
    for (int k = 0; k < 4; ++k) {
        int m = tid + k * NT;
        if (m < M && m < MAXBOX * 4) {
            float cx = bboxes[4*m+0] * (float)W_DIM;
            float cy = bboxes[4*m+1] * (float)H_DIM;
            float bw = bboxes[4*m+2] * (float)W_DIM;
            float bh = bboxes[4*m+3] * (float)H_DIM;
            int x1 = (int)fminf(fmaxf(cx - bw*0.5f, 0.0f), (float)(W_DIM-1));
            int y1 = (int)fminf(fmaxf(cy - bh*0.5f, 0.0f), (float)(H_DIM-1));
            int x2 = (int)fminf(fmaxf(cx + bw*0.5f, 0.0f), (float)(W_DIM-1));
            int y2 = (int)fminf(fmaxf(cy + bh*0.5f, 0.0f), (float)(H_DIM-1));
            int b  = batch_idx[m];
            b = min(max(b, 0), B_IMG-1);
            my_b[k] = b;
            my_p[k] = atomicAdd(&s_cnt[b], 1);  // rank within bucket (order-free union)
            my_y[k] = make_int2(y1, y2);
            my_x[k] = make_int2(x1, x2);
        } else {
            my_b[k] = -1;
        }
    }
    __syncthreads();
    if (tid == 0) {                             // 16-entry serial prefix
        int acc = 0;
        for (int b = 0; b < B_IMG; ++b) { s_start[b] = acc; acc += s_cnt[b]; }
    }
    __syncthreads();
#pragma unroll
    for (int k = 0; k < 4; ++k) {
        if (my_b[k] >= 0) {
            int idx = s_start[my_b[k]] + my_p[k];
            if (idx < MAXBOX) { s_yiv[idx] = my_y[k]; s_xiv[idx] = my_x[k]; }
        }
    }
    if (tid < B_IMG)
        s_eff[tid] = (is_seg[tid] == 0 && s_cnt[tid] > 0) ? 1 : 0;
    __syncthreads();

    // --- streaming pixel loop, float4 granularity ---
    float sp_sum = 0.0f, mx_sum = 0.0f;
    for (int t = blockIdx.x * NT + tid; t < T4; t += GRID * NT) {
        int b = t / IMG4;
        if (!s_eff[b]) continue;                // non-eff: analytic ln2 in K2
        int r  = t - b * IMG4;
        int y  = r / W4;
        int x0 = (r - y * W4) * 4;

        float4 v = seg4[t];
        sp_sum += softplus_fast(v.x) + softplus_fast(v.y)
                + softplus_fast(v.z) + softplus_fast(v.w);

        unsigned mb = 0;
        const int s = s_start[b], e = s + s_cnt[b];
        for (int i = s; i < e; ++i) {
            int2 yv = s_yiv[i];
            if (y >= yv.x && y <= yv.y) {
                int2 xv = s_xiv[i];
                mb |= (x0   >= xv.x && x0   <= xv.y) ? 1u : 0u;
                mb |= (x0+1 >= xv.x && x0+1 <= xv.y) ? 2u : 0u;
                mb |= (x0+2 >= xv.x && x0+2 <= xv.y) ? 4u : 0u;
                mb |= (x0+3 >= xv.x && x0+3 <= xv.y) ? 8u : 0u;
            }
        }
        mx_sum += ((mb & 1u) ? v.x : 0.0f) + ((mb & 2u) ? v.y : 0.0f)
                + ((mb & 4u) ? v.z : 0.0f) + ((mb & 8u) ? v.w : 0.0f);
    }

    // --- deterministic block reduce: butterfly within wave, LDS across waves ---
#pragma unroll
    for (int s = 32; s > 0; s >>= 1) {
        sp_sum += __shfl_xor(sp_sum, s, 64);
        mx_sum += __shfl_xor(mx_sum, s, 64);
    }
    const int wave = tid >> 6;
    if ((tid & 63) == 0) { red1[wave] = sp_sum; red2[wave] = mx_sum; }
    __syncthreads();
    if (tid == 0) {
        float a1 = 0.0f, a2 = 0.0f;
#pragma unroll
        for (int w = 0; w < NT / 64; ++w) { a1 += red1[w]; a2 += red2[w]; }
        partial[blockIdx.x] = make_float2(a1, a2);
    }
}

// ---------------------------------------------------------------------------
// Kernel 2: deterministic final reduction + eff bookkeeping + loss assembly.
// ---------------------------------------------------------------------------
__global__ void __launch_bounds__(NT)
final_reduce(const float2* __restrict__ partial,
             const int*    __restrict__ batch_idx,
             const unsigned char* __restrict__ is_seg,
             int M,
             float* __restrict__ out)
{
    __shared__ int   s_has[B_IMG];
    __shared__ float s1[NT / 64];
    __shared__ float s2[NT / 64];
    const int tid = threadIdx.x;
    if (tid < B_IMG) s_has[tid] = 0;
    __syncthreads();
    for (int m = tid; m < M; m += NT) {
        int b = batch_idx[m];
        b = min(max(b, 0), B_IMG-1);
        s_has[b] = 1;                          // benign race
    }
    __syncthreads();

    float a1 = 0.0f, a2 = 0.0f;
    for (int i = tid; i < GRID; i += NT) {     // fixed per-thread order
        float2 p = partial[i];
        a1 += p.x; a2 += p.y;
    }
#pragma unroll
    for (int s = 32; s > 0; s >>= 1) {
        a1 += __shfl_xor(a1, s, 64);
        a2 += __shfl_xor(a2, s, 64);
    }
    const int wave = tid >> 6;
    if ((tid & 63) == 0) { s1[wave] = a1; s2[wave] = a2; }
    __syncthreads();
    if (tid == 0) {
        float t1 = 0.0f, t2 = 0.0f;
#pragma unroll
        for (int w = 0; w < NT / 64; ++w) { t1 += s1[w]; t2 += s2[w]; }
        int n_eff = 0;
        for (int b = 0; b < B_IMG; ++b)
            n_eff += (is_seg[b] == 0 && s_has[b]) ? 1 : 0;
        float noneff_px = (float)(B_IMG - n_eff) * (float)H_DIM * (float)W_DIM;
        float total = t1 - t2 + LN2F * noneff_px;
        float loss  = LOSS_WEIGHT * (total / NPIX);
        out[0] = (n_eff > 0) ? loss : 0.0f;
    }
}

// ---------------------------------------------------------------------------
extern "C" void kernel_launch(void* const* d_in, const int* in_sizes, int n_in,
                              void* d_out, int out_size, void* d_ws, size_t ws_size,
                              hipStream_t stream) {
    const float4*        seg4      = (const float4*)d_in[0];
    const float*         bboxes    = (const float*)d_in[1];
    const int*           batch_idx = (const int*)d_in[2];
    const unsigned char* is_seg    = (const unsigned char*)d_in[3];
    float*               out       = (float*)d_out;
    const int M = in_sizes[1] / 4;

    float2* partial = (float2*)d_ws;           // GRID * 8 bytes

    fused_reduce<<<GRID, NT, 0, stream>>>(seg4, bboxes, batch_idx, is_seg, M, partial);
    final_reduce<<<1, NT, 0, stream>>>(partial, batch_idx, is_seg, M, out);
}